// Round 1
// baseline (9592.490 us; speedup 1.0000x reference)
//
#include <hip/hip_runtime.h>
#include <hip/hip_bf16.h>

// Swin block, fixed shapes: B=8, H=W=224, C=192, WS=7, SHIFT=3, NH=6, HD=32, DFF=768
// Windows tile exactly (224/7=32), no padding. Roll(-3,-3) handled by index math.
// Kernel A: per-(batch,window) fused LN1 + QKV + windowed attention + proj + residual.
// Kernel B: per-16-tokens fused LN2 + MLP(gelu exact) + residual, in-place on d_out.

#define CDIM 192
#define NH6 6
#define HD32 32
#define NTOK 49
#define DFFX 768
#define HW224 224
#define LTOK 50176

__device__ __forceinline__ int region_id(int p) {
    // region ids on the rolled canvas: [0,217)=0, [217,221)=1, [221,224)=2
    return (p < 217) ? 0 : ((p < 221) ? 1 : 2);
}

__global__ __launch_bounds__(192) void attn_kernel(
    const float* __restrict__ x,
    const float* __restrict__ qkv_w, const float* __restrict__ qkv_b,
    const float* __restrict__ proj_w, const float* __restrict__ proj_b,
    const float* __restrict__ rpb,
    const float* __restrict__ n1w, const float* __restrict__ n1b,
    float* __restrict__ y)
{
    __shared__ float hn[NTOK][CDIM];            // 37,632 B  LN'd window tokens
    __shared__ float qs[NTOK][HD32];            //  6,272 B  q (scaled); reused as attn-out
    __shared__ __hip_bfloat16 ksb[NTOK][HD32];  //  3,136 B  k (bf16)
    __shared__ float vs[NTOK][HD32];            //  6,272 B  v
    __shared__ float ps[NTOK][NTOK];            //  9,604 B  scores / probs
    __shared__ int   regid[NTOK];               // total ~63.1 KB (<64KB, 2 blocks/CU)

    const int tid = threadIdx.x;
    const int b  = blockIdx.x >> 10;
    const int w  = blockIdx.x & 1023;
    const int wr = w >> 5, wc = w & 31;

    if (tid < NTOK) {
        int r = tid / 7, cn = tid % 7;
        regid[tid] = region_id(wr*7 + r) * 3 + region_id(wc*7 + cn);
    }

    const int wv = tid >> 6, lane = tid & 63;
    // ---- LN1 + rolled gather ----
    for (int n = wv; n < NTOK; n += 3) {
        int r = n / 7, cn = n % 7;
        int hh = (wr*7 + r + 3) % HW224;
        int ww = (wc*7 + cn + 3) % HW224;
        const float* xp = x + ((size_t)b * LTOK + hh*HW224 + ww) * CDIM;
        float v0 = xp[lane], v1 = xp[lane+64], v2 = xp[lane+128];
        float s = v0+v1+v2, s2 = v0*v0+v1*v1+v2*v2;
        #pragma unroll
        for (int off = 32; off > 0; off >>= 1) {
            s  += __shfl_down(s, off);
            s2 += __shfl_down(s2, off);
        }
        s = __shfl(s, 0); s2 = __shfl(s2, 0);
        float mean = s * (1.0f/CDIM);
        float var  = s2 * (1.0f/CDIM) - mean*mean;
        float rstd = rsqrtf(var + 1e-5f);
        hn[n][lane]     = (v0-mean)*rstd*n1w[lane]     + n1b[lane];
        hn[n][lane+64]  = (v1-mean)*rstd*n1w[lane+64]  + n1b[lane+64];
        hn[n][lane+128] = (v2-mean)*rstd*n1w[lane+128] + n1b[lane+128];
    }
    __syncthreads();

    float po[NTOK];   // proj output accumulator, one column (=tid) per thread
    #pragma unroll
    for (int n = 0; n < NTOK; ++n) po[n] = 0.0f;

    const float qscale = 0.17677669529663689f;  // 1/sqrt(32)

    for (int h = 0; h < NH6; ++h) {
        // ---- QKV for head h: 96 cols (q|k|v x 32), tile 4 cols x ~6 rows / thread ----
        {
            int cq = tid % 24;            // col-quad: cols cq*4..cq*4+3 of the 96
            int rg = tid / 24;            // row group 0..7
            int r0 = rg * 6;
            int nr = (rg == 7) ? 7 : 6;   // rows 42..48 for the last group
            int part  = cq >> 3;          // 0=q 1=k 2=v
            int jbase = (cq & 7) * 4;
            int col0  = part*192 + h*32 + jbase;
            float acc[4][7];
            #pragma unroll
            for (int q = 0; q < 4; ++q)
                #pragma unroll
                for (int i = 0; i < 7; ++i) acc[q][i] = 0.0f;
            for (int k = 0; k < CDIM; k += 4) {
                float4 hv[7];
                #pragma unroll
                for (int i = 0; i < 7; ++i) hv[i] = *(const float4*)&hn[r0+i][k]; // r0+6<=48 safe
                #pragma unroll
                for (int kk = 0; kk < 4; ++kk) {
                    float4 w4 = *(const float4*)&qkv_w[(size_t)(k+kk)*576 + col0];
                    #pragma unroll
                    for (int i = 0; i < 7; ++i) {
                        float hvv = (kk==0)?hv[i].x:((kk==1)?hv[i].y:((kk==2)?hv[i].z:hv[i].w));
                        acc[0][i] += hvv*w4.x;
                        acc[1][i] += hvv*w4.y;
                        acc[2][i] += hvv*w4.z;
                        acc[3][i] += hvv*w4.w;
                    }
                }
            }
            float qb0 = qkv_b[col0],   qb1 = qkv_b[col0+1];
            float qb2 = qkv_b[col0+2], qb3 = qkv_b[col0+3];
            #pragma unroll
            for (int i = 0; i < 7; ++i) {
                if (i < nr) {
                    int n = r0 + i;
                    float v0 = acc[0][i]+qb0, v1 = acc[1][i]+qb1;
                    float v2 = acc[2][i]+qb2, v3 = acc[3][i]+qb3;
                    if (part == 0) {
                        qs[n][jbase+0] = v0*qscale; qs[n][jbase+1] = v1*qscale;
                        qs[n][jbase+2] = v2*qscale; qs[n][jbase+3] = v3*qscale;
                    } else if (part == 1) {
                        ksb[n][jbase+0] = __float2bfloat16(v0);
                        ksb[n][jbase+1] = __float2bfloat16(v1);
                        ksb[n][jbase+2] = __float2bfloat16(v2);
                        ksb[n][jbase+3] = __float2bfloat16(v3);
                    } else {
                        vs[n][jbase+0] = v0; vs[n][jbase+1] = v1;
                        vs[n][jbase+2] = v2; vs[n][jbase+3] = v3;
                    }
                }
            }
        }
        __syncthreads();

        // ---- scores: q.k + rel-pos bias + region mask ----
        for (int o = tid; o < NTOK*NTOK; o += 192) {
            int n = o / NTOK, m = o % NTOK;
            float a = 0.0f;
            #pragma unroll
            for (int j = 0; j < HD32; ++j)
                a += qs[n][j] * __bfloat162float(ksb[m][j]);
            int dh = n/7 - m/7 + 6;
            int dw = n%7 - m%7 + 6;
            a += rpb[(dh*13 + dw)*NH6 + h];
            if (regid[n] != regid[m]) a -= 100.0f;
            ps[n][m] = a;
        }
        __syncthreads();

        // ---- softmax rows ----
        if (tid < NTOK) {
            float mx = -1e30f;
            #pragma unroll
            for (int m = 0; m < NTOK; ++m) mx = fmaxf(mx, ps[tid][m]);
            float sum = 0.0f;
            #pragma unroll
            for (int m = 0; m < NTOK; ++m) {
                float e = __expf(ps[tid][m] - mx);
                ps[tid][m] = e;
                sum += e;
            }
            float inv = 1.0f / sum;
            #pragma unroll
            for (int m = 0; m < NTOK; ++m) ps[tid][m] *= inv;
        }
        __syncthreads();

        // ---- PV: attn-out into qs (q no longer needed this head) ----
        for (int o = tid; o < NTOK*HD32; o += 192) {
            int n = o >> 5, j = o & 31;
            float a = 0.0f;
            #pragma unroll
            for (int m = 0; m < NTOK; ++m) a += ps[n][m] * vs[m][j];
            qs[n][j] = a;
        }
        __syncthreads();

        // ---- proj partial accumulation: out col = tid ----
        for (int k = 0; k < HD32; k += 4) {
            int kf = h*32 + k;
            float w0  = proj_w[(size_t)kf*192 + tid];
            float w1v = proj_w[(size_t)(kf+1)*192 + tid];
            float w2v = proj_w[(size_t)(kf+2)*192 + tid];
            float w3v = proj_w[(size_t)(kf+3)*192 + tid];
            #pragma unroll
            for (int n = 0; n < NTOK; ++n) {
                float4 a4 = *(const float4*)&qs[n][k];
                po[n] += a4.x*w0 + a4.y*w1v + a4.z*w2v + a4.w*w3v;
            }
        }
        __syncthreads();
    }

    // ---- epilogue: residual + proj bias, scatter to original (un-rolled) positions ----
    float pb = proj_b[tid];
    #pragma unroll
    for (int n = 0; n < NTOK; ++n) {
        int r = n / 7, cn = n % 7;
        int hh = (wr*7 + r + 3) % HW224;
        int ww = (wc*7 + cn + 3) % HW224;
        size_t idx = ((size_t)b * LTOK + hh*HW224 + ww) * CDIM + tid;
        y[idx] = x[idx] + po[n] + pb;
    }
}

__global__ __launch_bounds__(192) void mlp_kernel(
    float* __restrict__ y,
    const float* __restrict__ n2w, const float* __restrict__ n2b,
    const float* __restrict__ w1, const float* __restrict__ b1,
    const float* __restrict__ w2, const float* __restrict__ b2)
{
    __shared__ float xn[16][CDIM];   // 12,288 B
    __shared__ float hid[16][DFFX];  // 49,152 B  (total 61,440 < 64KB, 2 blocks/CU)

    const int tid = threadIdx.x;
    const size_t g0 = (size_t)blockIdx.x * 16;

    const int wv = tid >> 6, lane = tid & 63;
    // ---- LN2 ----
    for (int t = wv; t < 16; t += 3) {
        const float* xp = y + (g0 + t) * CDIM;
        float v0 = xp[lane], v1 = xp[lane+64], v2 = xp[lane+128];
        float s = v0+v1+v2, s2 = v0*v0+v1*v1+v2*v2;
        #pragma unroll
        for (int off = 32; off > 0; off >>= 1) {
            s  += __shfl_down(s, off);
            s2 += __shfl_down(s2, off);
        }
        s = __shfl(s, 0); s2 = __shfl(s2, 0);
        float mean = s * (1.0f/CDIM);
        float var  = s2 * (1.0f/CDIM) - mean*mean;
        float rstd = rsqrtf(var + 1e-5f);
        xn[t][lane]     = (v0-mean)*rstd*n2w[lane]     + n2b[lane];
        xn[t][lane+64]  = (v1-mean)*rstd*n2w[lane+64]  + n2b[lane+64];
        xn[t][lane+128] = (v2-mean)*rstd*n2w[lane+128] + n2b[lane+128];
    }
    __syncthreads();

    // ---- hidden = gelu(xn @ w1 + b1): 4 cols x 16 tokens per thread ----
    {
        float acc[4][16];
        #pragma unroll
        for (int q = 0; q < 4; ++q)
            #pragma unroll
            for (int t = 0; t < 16; ++t) acc[q][t] = 0.0f;
        for (int k = 0; k < CDIM; k += 4) {
            float4 h4[16];
            #pragma unroll
            for (int t = 0; t < 16; ++t) h4[t] = *(const float4*)&xn[t][k];
            #pragma unroll
            for (int q = 0; q < 4; ++q) {
                int c = tid + 192*q;
                float wa = w1[(size_t)k*DFFX + c];
                float wb = w1[(size_t)(k+1)*DFFX + c];
                float wcc = w1[(size_t)(k+2)*DFFX + c];
                float wd = w1[(size_t)(k+3)*DFFX + c];
                #pragma unroll
                for (int t = 0; t < 16; ++t)
                    acc[q][t] += h4[t].x*wa + h4[t].y*wb + h4[t].z*wcc + h4[t].w*wd;
            }
        }
        #pragma unroll
        for (int q = 0; q < 4; ++q) {
            int c = tid + 192*q;
            float bv = b1[c];
            #pragma unroll
            for (int t = 0; t < 16; ++t) {
                float v = acc[q][t] + bv;
                hid[t][c] = 0.5f*v*(1.0f + erff(v*0.70710678118654752f));
            }
        }
    }
    __syncthreads();

    // ---- out = hid @ w2 + b2 + residual: 2 cols x 8 tokens per thread ----
    {
        int c2 = tid % 96;
        int tg = tid / 96;
        int t0 = tg * 8;
        float acc2[2][8];
        #pragma unroll
        for (int q = 0; q < 2; ++q)
            #pragma unroll
            for (int i = 0; i < 8; ++i) acc2[q][i] = 0.0f;
        for (int k = 0; k < DFFX; k += 4) {
            float4 hv[8];
            #pragma unroll
            for (int i = 0; i < 8; ++i) hv[i] = *(const float4*)&hid[t0+i][k];
            #pragma unroll
            for (int q = 0; q < 2; ++q) {
                int c = c2 + 96*q;
                float wa = w2[(size_t)k*CDIM + c];
                float wb = w2[(size_t)(k+1)*CDIM + c];
                float wcc = w2[(size_t)(k+2)*CDIM + c];
                float wd = w2[(size_t)(k+3)*CDIM + c];
                #pragma unroll
                for (int i = 0; i < 8; ++i)
                    acc2[q][i] += hv[i].x*wa + hv[i].y*wb + hv[i].z*wcc + hv[i].w*wd;
            }
        }
        #pragma unroll
        for (int q = 0; q < 2; ++q) {
            int c = c2 + 96*q;
            float bv = b2[c];
            #pragma unroll
            for (int i = 0; i < 8; ++i) {
                size_t idx = (g0 + t0 + i) * CDIM + c;
                y[idx] = y[idx] + acc2[q][i] + bv;
            }
        }
    }
}

extern "C" void kernel_launch(void* const* d_in, const int* in_sizes, int n_in,
                              void* d_out, int out_size, void* d_ws, size_t ws_size,
                              hipStream_t stream) {
    (void)in_sizes; (void)n_in; (void)d_ws; (void)ws_size; (void)out_size;
    const float* x      = (const float*)d_in[0];
    // d_in[1], d_in[2] are H, W (ints) — fixed at 224, hardcoded.
    const float* qkv_w  = (const float*)d_in[3];
    const float* qkv_b  = (const float*)d_in[4];
    const float* proj_w = (const float*)d_in[5];
    const float* proj_b = (const float*)d_in[6];
    const float* rpb    = (const float*)d_in[7];
    const float* n1w    = (const float*)d_in[8];
    const float* n1b    = (const float*)d_in[9];
    const float* n2w    = (const float*)d_in[10];
    const float* n2b    = (const float*)d_in[11];
    const float* w1     = (const float*)d_in[12];
    const float* b1     = (const float*)d_in[13];
    const float* w2     = (const float*)d_in[14];
    const float* b2     = (const float*)d_in[15];
    float* out = (float*)d_out;

    // y = x + proj(attn(LN1(x)))   (8 batches x 1024 windows)
    attn_kernel<<<dim3(8 * 1024), dim3(192), 0, stream>>>(
        x, qkv_w, qkv_b, proj_w, proj_b, rpb, n1w, n1b, out);
    // y = y + mlp(LN2(y))          (401408 tokens / 16 per block)
    mlp_kernel<<<dim3(401408 / 16), dim3(192), 0, stream>>>(
        out, n2w, n2b, w1, b1, w2, b2);
}

// Round 2
// 6495.072 us; speedup vs baseline: 1.4769x; 1.4769x over previous
//
#include <hip/hip_runtime.h>
#include <hip/hip_bf16.h>

// Swin block, fixed shapes: B=8, H=W=224, C=192, WS=7, SHIFT=3, NH=6, HD=32, DFF=768
// Kernel A (unchanged fp32): per-(batch,window) fused LN1 + QKV + attention + proj + residual.
// Kernel prep: transpose w1/w2 to bf16 [n][k] layout in d_ws for MFMA B-fragments.
// Kernel B (NEW): 32 tokens/block, LN2 + GEMM1(MFMA bf16) + GELU + GEMM2(MFMA bf16) + residual.

#define CDIM 192
#define NH6 6
#define HD32 32
#define NTOK 49
#define DFFX 768
#define HW224 224
#define LTOK 50176

typedef __bf16 bf16x8 __attribute__((ext_vector_type(8)));
typedef float  f32x4  __attribute__((ext_vector_type(4)));

__device__ __forceinline__ int region_id(int p) {
    return (p < 217) ? 0 : ((p < 221) ? 1 : 2);
}

__global__ __launch_bounds__(192) void attn_kernel(
    const float* __restrict__ x,
    const float* __restrict__ qkv_w, const float* __restrict__ qkv_b,
    const float* __restrict__ proj_w, const float* __restrict__ proj_b,
    const float* __restrict__ rpb,
    const float* __restrict__ n1w, const float* __restrict__ n1b,
    float* __restrict__ y)
{
    __shared__ float hn[NTOK][CDIM];
    __shared__ float qs[NTOK][HD32];
    __shared__ __hip_bfloat16 ksb[NTOK][HD32];
    __shared__ float vs[NTOK][HD32];
    __shared__ float ps[NTOK][NTOK];
    __shared__ int   regid[NTOK];

    const int tid = threadIdx.x;
    const int b  = blockIdx.x >> 10;
    const int w  = blockIdx.x & 1023;
    const int wr = w >> 5, wc = w & 31;

    if (tid < NTOK) {
        int r = tid / 7, cn = tid % 7;
        regid[tid] = region_id(wr*7 + r) * 3 + region_id(wc*7 + cn);
    }

    const int wv = tid >> 6, lane = tid & 63;
    for (int n = wv; n < NTOK; n += 3) {
        int r = n / 7, cn = n % 7;
        int hh = (wr*7 + r + 3) % HW224;
        int ww = (wc*7 + cn + 3) % HW224;
        const float* xp = x + ((size_t)b * LTOK + hh*HW224 + ww) * CDIM;
        float v0 = xp[lane], v1 = xp[lane+64], v2 = xp[lane+128];
        float s = v0+v1+v2, s2 = v0*v0+v1*v1+v2*v2;
        #pragma unroll
        for (int off = 32; off > 0; off >>= 1) {
            s  += __shfl_down(s, off);
            s2 += __shfl_down(s2, off);
        }
        s = __shfl(s, 0); s2 = __shfl(s2, 0);
        float mean = s * (1.0f/CDIM);
        float var  = s2 * (1.0f/CDIM) - mean*mean;
        float rstd = rsqrtf(var + 1e-5f);
        hn[n][lane]     = (v0-mean)*rstd*n1w[lane]     + n1b[lane];
        hn[n][lane+64]  = (v1-mean)*rstd*n1w[lane+64]  + n1b[lane+64];
        hn[n][lane+128] = (v2-mean)*rstd*n1w[lane+128] + n1b[lane+128];
    }
    __syncthreads();

    float po[NTOK];
    #pragma unroll
    for (int n = 0; n < NTOK; ++n) po[n] = 0.0f;

    const float qscale = 0.17677669529663689f;

    for (int h = 0; h < NH6; ++h) {
        {
            int cq = tid % 24;
            int rg = tid / 24;
            int r0 = rg * 6;
            int nr = (rg == 7) ? 7 : 6;
            int part  = cq >> 3;
            int jbase = (cq & 7) * 4;
            int col0  = part*192 + h*32 + jbase;
            float acc[4][7];
            #pragma unroll
            for (int q = 0; q < 4; ++q)
                #pragma unroll
                for (int i = 0; i < 7; ++i) acc[q][i] = 0.0f;
            for (int k = 0; k < CDIM; k += 4) {
                float4 hv[7];
                #pragma unroll
                for (int i = 0; i < 7; ++i) hv[i] = *(const float4*)&hn[r0+i][k];
                #pragma unroll
                for (int kk = 0; kk < 4; ++kk) {
                    float4 w4 = *(const float4*)&qkv_w[(size_t)(k+kk)*576 + col0];
                    #pragma unroll
                    for (int i = 0; i < 7; ++i) {
                        float hvv = (kk==0)?hv[i].x:((kk==1)?hv[i].y:((kk==2)?hv[i].z:hv[i].w));
                        acc[0][i] += hvv*w4.x;
                        acc[1][i] += hvv*w4.y;
                        acc[2][i] += hvv*w4.z;
                        acc[3][i] += hvv*w4.w;
                    }
                }
            }
            float qb0 = qkv_b[col0],   qb1 = qkv_b[col0+1];
            float qb2 = qkv_b[col0+2], qb3 = qkv_b[col0+3];
            #pragma unroll
            for (int i = 0; i < 7; ++i) {
                if (i < nr) {
                    int n = r0 + i;
                    float v0 = acc[0][i]+qb0, v1 = acc[1][i]+qb1;
                    float v2 = acc[2][i]+qb2, v3 = acc[3][i]+qb3;
                    if (part == 0) {
                        qs[n][jbase+0] = v0*qscale; qs[n][jbase+1] = v1*qscale;
                        qs[n][jbase+2] = v2*qscale; qs[n][jbase+3] = v3*qscale;
                    } else if (part == 1) {
                        ksb[n][jbase+0] = __float2bfloat16(v0);
                        ksb[n][jbase+1] = __float2bfloat16(v1);
                        ksb[n][jbase+2] = __float2bfloat16(v2);
                        ksb[n][jbase+3] = __float2bfloat16(v3);
                    } else {
                        vs[n][jbase+0] = v0; vs[n][jbase+1] = v1;
                        vs[n][jbase+2] = v2; vs[n][jbase+3] = v3;
                    }
                }
            }
        }
        __syncthreads();

        for (int o = tid; o < NTOK*NTOK; o += 192) {
            int n = o / NTOK, m = o % NTOK;
            float a = 0.0f;
            #pragma unroll
            for (int j = 0; j < HD32; ++j)
                a += qs[n][j] * __bfloat162float(ksb[m][j]);
            int dh = n/7 - m/7 + 6;
            int dw = n%7 - m%7 + 6;
            a += rpb[(dh*13 + dw)*NH6 + h];
            if (regid[n] != regid[m]) a -= 100.0f;
            ps[n][m] = a;
        }
        __syncthreads();

        if (tid < NTOK) {
            float mx = -1e30f;
            #pragma unroll
            for (int m = 0; m < NTOK; ++m) mx = fmaxf(mx, ps[tid][m]);
            float sum = 0.0f;
            #pragma unroll
            for (int m = 0; m < NTOK; ++m) {
                float e = __expf(ps[tid][m] - mx);
                ps[tid][m] = e;
                sum += e;
            }
            float inv = 1.0f / sum;
            #pragma unroll
            for (int m = 0; m < NTOK; ++m) ps[tid][m] *= inv;
        }
        __syncthreads();

        for (int o = tid; o < NTOK*HD32; o += 192) {
            int n = o >> 5, j = o & 31;
            float a = 0.0f;
            #pragma unroll
            for (int m = 0; m < NTOK; ++m) a += ps[n][m] * vs[m][j];
            qs[n][j] = a;
        }
        __syncthreads();

        for (int k = 0; k < HD32; k += 4) {
            int kf = h*32 + k;
            float w0  = proj_w[(size_t)kf*192 + tid];
            float w1v = proj_w[(size_t)(kf+1)*192 + tid];
            float w2v = proj_w[(size_t)(kf+2)*192 + tid];
            float w3v = proj_w[(size_t)(kf+3)*192 + tid];
            #pragma unroll
            for (int n = 0; n < NTOK; ++n) {
                float4 a4 = *(const float4*)&qs[n][k];
                po[n] += a4.x*w0 + a4.y*w1v + a4.z*w2v + a4.w*w3v;
            }
        }
        __syncthreads();
    }

    float pb = proj_b[tid];
    #pragma unroll
    for (int n = 0; n < NTOK; ++n) {
        int r = n / 7, cn = n % 7;
        int hh = (wr*7 + r + 3) % HW224;
        int ww = (wc*7 + cn + 3) % HW224;
        size_t idx = ((size_t)b * LTOK + hh*HW224 + ww) * CDIM + tid;
        y[idx] = x[idx] + po[n] + pb;
    }
}

// ---- weight prep: w1 [192][768] -> w1t bf16 [n=768][k=192]; w2 [768][192] -> w2t bf16 [n=192][k=768]
__global__ __launch_bounds__(256) void prep_kernel(
    const float* __restrict__ w1, const float* __restrict__ w2,
    __bf16* __restrict__ w1t, __bf16* __restrict__ w2t)
{
    int i = blockIdx.x * 256 + threadIdx.x;
    if (i < 192*768) {
        int k1 = i / 768, n1 = i % 768;
        w1t[n1*192 + k1] = (__bf16)w1[i];
        int k2 = i / 192, n2 = i % 192;
        w2t[n2*768 + k2] = (__bf16)w2[i];
    }
}

// ---- MLP: 32 tokens/block, MFMA bf16 16x16x32 ----
// GEMM1: [32x192]x[192x768], GEMM2: [32x768]x[768x192]. B-frags streamed from L2 (w1t/w2t).
#define XPAD 200   // 192+8: row stride 400B -> 2-way LDS alias (free)
#define HPAD 776   // 768+8: row stride 1552B -> 2-way LDS alias (free)

__global__ __launch_bounds__(256) void mlp_kernel(
    float* __restrict__ y,
    const float* __restrict__ n2w, const float* __restrict__ n2b,
    const __bf16* __restrict__ w1t, const float* __restrict__ b1,
    const __bf16* __restrict__ w2t, const float* __restrict__ b2)
{
    __shared__ __attribute__((aligned(16))) __bf16 xnb[32][XPAD];  // 12,800 B
    __shared__ __attribute__((aligned(16))) __bf16 hid[32][HPAD];  // 49,664 B (total 62,464)

    const int tid = threadIdx.x;
    const int wv = tid >> 6, lane = tid & 63;
    const int ln = lane & 15, quad = lane >> 4;
    const size_t g0 = (size_t)blockIdx.x * 32;

    // ---- LN2: one wave per token ----
    for (int t = wv; t < 32; t += 4) {
        const float* xp = y + (g0 + t) * CDIM;
        float v0 = xp[lane], v1 = xp[lane+64], v2 = xp[lane+128];
        float s = v0+v1+v2, s2 = v0*v0+v1*v1+v2*v2;
        #pragma unroll
        for (int off = 32; off > 0; off >>= 1) {
            s  += __shfl_down(s, off);
            s2 += __shfl_down(s2, off);
        }
        s = __shfl(s, 0); s2 = __shfl(s2, 0);
        float mean = s * (1.0f/CDIM);
        float var  = s2 * (1.0f/CDIM) - mean*mean;
        float rstd = rsqrtf(var + 1e-5f);
        xnb[t][lane]     = (__bf16)((v0-mean)*rstd*n2w[lane]     + n2b[lane]);
        xnb[t][lane+64]  = (__bf16)((v1-mean)*rstd*n2w[lane+64]  + n2b[lane+64]);
        xnb[t][lane+128] = (__bf16)((v2-mean)*rstd*n2w[lane+128] + n2b[lane+128]);
    }
    __syncthreads();

    // ---- GEMM1 + GELU -> hid ----
    // wave wv owns N-tiles nt = wv*12 .. wv*12+11 (16 cols each); M-tiles 0,1 (rows 0-15,16-31)
    {
        f32x4 acc[2][12];
        #pragma unroll
        for (int mt = 0; mt < 2; ++mt)
            #pragma unroll
            for (int j = 0; j < 12; ++j) acc[mt][j] = (f32x4){0.f,0.f,0.f,0.f};

        for (int ks = 0; ks < 6; ++ks) {           // K = 6 * 32
            const int kb = ks*32 + quad*8;
            bf16x8 a0 = *(const bf16x8*)&xnb[ln][kb];
            bf16x8 a1 = *(const bf16x8*)&xnb[16+ln][kb];
            #pragma unroll
            for (int j = 0; j < 12; ++j) {
                const int nt = wv*12 + j;
                bf16x8 bfr = *(const bf16x8*)(w1t + (size_t)(nt*16 + ln)*192 + kb);
                acc[0][j] = __builtin_amdgcn_mfma_f32_16x16x32_bf16(a0, bfr, acc[0][j], 0, 0, 0);
                acc[1][j] = __builtin_amdgcn_mfma_f32_16x16x32_bf16(a1, bfr, acc[1][j], 0, 0, 0);
            }
        }
        // epilogue: bias + exact GELU -> hid (D layout: col = ln, row = quad*4 + r)
        #pragma unroll
        for (int j = 0; j < 12; ++j) {
            const int c = (wv*12 + j)*16 + ln;
            const float bias = b1[c];
            #pragma unroll
            for (int mt = 0; mt < 2; ++mt) {
                #pragma unroll
                for (int r = 0; r < 4; ++r) {
                    int t = mt*16 + quad*4 + r;
                    float v = acc[mt][j][r] + bias;
                    hid[t][c] = (__bf16)(0.5f*v*(1.0f + erff(v*0.70710678118654752f)));
                }
            }
        }
    }
    __syncthreads();

    // ---- GEMM2 + residual ----
    // wave wv owns N-tiles nt = wv*3 .. wv*3+2 (covers 192 cols)
    {
        f32x4 acc[2][3];
        #pragma unroll
        for (int mt = 0; mt < 2; ++mt)
            #pragma unroll
            for (int j = 0; j < 3; ++j) acc[mt][j] = (f32x4){0.f,0.f,0.f,0.f};

        for (int ks = 0; ks < 24; ++ks) {          // K = 24 * 32
            const int kb = ks*32 + quad*8;
            bf16x8 a0 = *(const bf16x8*)&hid[ln][kb];
            bf16x8 a1 = *(const bf16x8*)&hid[16+ln][kb];
            #pragma unroll
            for (int j = 0; j < 3; ++j) {
                const int nt = wv*3 + j;
                bf16x8 bfr = *(const bf16x8*)(w2t + (size_t)(nt*16 + ln)*768 + kb);
                acc[0][j] = __builtin_amdgcn_mfma_f32_16x16x32_bf16(a0, bfr, acc[0][j], 0, 0, 0);
                acc[1][j] = __builtin_amdgcn_mfma_f32_16x16x32_bf16(a1, bfr, acc[1][j], 0, 0, 0);
            }
        }
        #pragma unroll
        for (int j = 0; j < 3; ++j) {
            const int c = (wv*3 + j)*16 + ln;
            const float bias = b2[c];
            #pragma unroll
            for (int mt = 0; mt < 2; ++mt) {
                #pragma unroll
                for (int r = 0; r < 4; ++r) {
                    int t = mt*16 + quad*4 + r;
                    size_t idx = (g0 + t) * CDIM + c;
                    y[idx] = y[idx] + acc[mt][j][r] + bias;
                }
            }
        }
    }
}

extern "C" void kernel_launch(void* const* d_in, const int* in_sizes, int n_in,
                              void* d_out, int out_size, void* d_ws, size_t ws_size,
                              hipStream_t stream) {
    (void)in_sizes; (void)n_in; (void)ws_size; (void)out_size;
    const float* x      = (const float*)d_in[0];
    const float* qkv_w  = (const float*)d_in[3];
    const float* qkv_b  = (const float*)d_in[4];
    const float* proj_w = (const float*)d_in[5];
    const float* proj_b = (const float*)d_in[6];
    const float* rpb    = (const float*)d_in[7];
    const float* n1w    = (const float*)d_in[8];
    const float* n1b    = (const float*)d_in[9];
    const float* n2w    = (const float*)d_in[10];
    const float* n2b    = (const float*)d_in[11];
    const float* w1     = (const float*)d_in[12];
    const float* b1     = (const float*)d_in[13];
    const float* w2     = (const float*)d_in[14];
    const float* b2     = (const float*)d_in[15];
    float* out = (float*)d_out;

    __bf16* w1t = (__bf16*)d_ws;                       // 147456 * 2B
    __bf16* w2t = (__bf16*)((char*)d_ws + 294912);     // 147456 * 2B

    prep_kernel<<<dim3(576), dim3(256), 0, stream>>>(w1, w2, w1t, w2t);
    attn_kernel<<<dim3(8 * 1024), dim3(192), 0, stream>>>(
        x, qkv_w, qkv_b, proj_w, proj_b, rpb, n1w, n1b, out);
    mlp_kernel<<<dim3(401408 / 32), dim3(256), 0, stream>>>(
        out, n2w, n2b, w1t, b1, w2t, b2);
}